// Round 7
// baseline (221.999 us; speedup 1.0000x reference)
//
#include <hip/hip_runtime.h>
#include <hip/hip_bf16.h>

#define NBLK  50000
#define NATOM 400000
#define NEDGE 800000
#define NBS   1563            // ceil(400000/256)

typedef __bf16 bf16x8 __attribute__((ext_vector_type(8)));
typedef float  f32x4  __attribute__((ext_vector_type(4)));

// ---- workspace layout (bytes); WS_NEED kept at the round-5/6-proven value ----
#define START_OFF 0UL          // int32[400001]: counts -> exclusive offsets (+total)
#define CUR_OFF   1600016UL    // int32[400000]: scatter cursors; REUSED as EW1 f32[100][128] after k_scatter
#define BS_OFF    3200016UL    // int32[1563]
#define REC_OFF   3206288UL    // u16 [800000]: per-edge pair ids, CSR by dst atom
#define T_OFF     4806288UL    // f32 [500][128]: msg table; REWRITTEN IN PLACE to TW1 = T@W1 by k_prep2
#define POS_OFF   5062288UL    // bf16[1024][128] sinusoid table
#define G2T_OFF   5357200UL    // bf16[128][128] gine_w2^T
#define M0T_OFF   5389968UL    // bf16[128][384] mlp_w0^T
#define M1T_OFF   5488272UL    // bf16[128][128] mlp_w1^T
#define M2T_OFF   5521040UL    // bf16[128][128] mlp_w2^T
#define GM_OFF    5553808UL    // u8 [50000] canonical generate_mask
#define FLAG_OFF  5603808UL    // int32 dtype-sniff flag
#define WS_NEED   18403840UL   // proven available in rounds 5-6

#define MFMA(a,b,c) __builtin_amdgcn_mfma_f32_16x16x32_bf16((a),(b),(c),0,0,0)

__device__ inline f32x4 splat4(float v){ f32x4 r; r[0]=v; r[1]=v; r[2]=v; r[3]=v; return r; }
__device__ inline float scrub(float v){ return (v==v && v<1e30f && v>-1e30f) ? v : 0.f; }

// ---------------- dtype sniff for generate_mask (1 block) ----------------
__global__ void k_sniff(const void* gm_raw, char* ws) {
  __shared__ int big;
  if (threadIdx.x == 0) big = 0;
  __syncthreads();
  const unsigned* gw = (const unsigned*)gm_raw;
  for (int i = threadIdx.x; i < 12500; i += 256)   // 50000 bytes either way: safe
    if (gw[i] > 1u) big = 1;
  __syncthreads();
  if (threadIdx.x == 0) *(int*)(ws + FLAG_OFF) = big;
}

// ------------- prep1: msg table T, sinusoid, W^T (f32->bf16), gm canon ----------
// blocks: [0,100) T, [100,1124) sinusoid, [1124,1172) transposes, [1172,1222) gm
__global__ void k_prep1(const float* atom_embed, const float* bond_embed,
                        const float* g2, const float* m0, const float* m1,
                        const float* m2, const void* gm_raw, char* ws) {
  int b = blockIdx.x, t = threadIdx.x;
  if (b < 100) {                       // T[a*5+bond][c] = relu(ae + be), f32
    float ae = atom_embed[b*128 + t];
    float* T = (float*)(ws + T_OFF);
    for (int bo = 0; bo < 5; ++bo) {
      float v = ae + bond_embed[bo*128 + t];
      T[(b*5 + bo)*128 + t] = v > 0.f ? v : 0.f;
    }
  } else if (b < 1124) {               // sinusoidal table, bf16, fast-math
    int p = b - 100;
    __bf16* P = (__bf16*)(ws + POS_OFF);
    int c = t & 63;
    float invf = exp2f((float)c * -0.20762050593046012f);  // 10000^(-c/64)
    float ang = (float)p * invf;
    float v = (t < 64) ? __sinf(ang) : __cosf(ang);
    P[p*128 + t] = (__bf16)v;
  } else if (b < 1172) {               // weight transposes f32 -> bf16 [n][k]
    int wb = b - 1124;
    const float* src; __bf16* dst; int K; int r0;
    if (wb < 8)       { src = g2; dst = (__bf16*)(ws + G2T_OFF); K = 128; r0 = wb*16; }
    else if (wb < 32) { src = m0; dst = (__bf16*)(ws + M0T_OFF); K = 384; r0 = (wb-8)*16; }
    else if (wb < 40) { src = m1; dst = (__bf16*)(ws + M1T_OFF); K = 128; r0 = (wb-32)*16; }
    else              { src = m2; dst = (__bf16*)(ws + M2T_OFF); K = 128; r0 = (wb-40)*16; }
    for (int rr = 0; rr < 16; ++rr) {
      int r = r0 + rr;
      dst[t*K + r] = (__bf16)src[r*128 + t];
    }
  } else {                             // gm canon: 50 blocks x 1000 elems
    int anyBig = *(const int*)(ws + FLAG_OFF);
    int base = (b - 1172) * 1000;
    unsigned char* gu = (unsigned char*)(ws + GM_OFF);
    if (anyBig) {
      const unsigned char* gb = (const unsigned char*)gm_raw;
      for (int i = t; i < 1000; i += 128) gu[base+i] = gb[base+i] ? 1 : 0;
    } else {
      const int* gi = (const int*)gm_raw;
      for (int i = t; i < 1000; i += 128) gu[base+i] = gi[base+i] ? 1 : 0;
    }
  }
}

// ------- prep2: EW1 = emb@W1+b1 (->CUR region), TW1 = T@W1 (in place over T) -----
__global__ void k_prep2(const float* atom_embed, const float* g1, const float* gb1,
                        char* ws) {
  int b = blockIdx.x, t = threadIdx.x;   // t = output col
  if (b < 100) {
    float s = gb1[t];
    const float* row = atom_embed + b*128;
    for (int k = 0; k < 128; ++k) s += row[k] * g1[k*128 + t];
    ((float*)(ws + CUR_OFF))[b*128 + t] = s;
  } else {
    int r = b - 100;                     // T row
    float* T = (float*)(ws + T_OFF);
    const float* row = T + r*128;
    float s = 0.f;
    for (int k = 0; k < 128; ++k) s += row[k] * g1[k*128 + t];
    __syncthreads();                     // all reads of row r done before overwrite
    T[r*128 + t] = s;                    // in-place TW1 (no bias: bias via EW1)
  }
}

// ---------------- count valid in-edges per dst atom ----------------
__global__ void k_count(const int* __restrict__ bonds, char* ws) {
  int e = blockIdx.x*256 + threadIdx.x;
  if (e >= NEDGE) return;
  const unsigned char* gm = (const unsigned char*)(ws + GM_OFF);
  int src = bonds[e*3], dst = bonds[e*3+1];
  if (gm[src >> 3] | gm[dst >> 3]) return;
  atomicAdd((int*)(ws + START_OFF) + dst, 1);
}

// ---------------- exclusive scan over 400000 counts (3 kernels) ----------------
__global__ void k_scan1(char* ws) {
  __shared__ int s[256];
  int b = blockIdx.x, t = threadIdx.x, i = b*256 + t;
  int* cnt = (int*)(ws + START_OFF);
  int v = (i < NATOM) ? cnt[i] : 0;
  s[t] = v; __syncthreads();
  for (int d = 1; d < 256; d <<= 1) {
    int x = (t >= d) ? s[t-d] : 0;
    __syncthreads(); s[t] += x; __syncthreads();
  }
  if (i < NATOM) cnt[i] = s[t] - v;
  if (t == 255) ((int*)(ws + BS_OFF))[b] = s[255];
}
__global__ void k_scan2(char* ws) {
  __shared__ int s[256]; __shared__ int carry;
  int t = threadIdx.x;
  int* bs = (int*)(ws + BS_OFF);
  if (t == 0) carry = 0;
  __syncthreads();
  for (int c = 0; c < 7; ++c) {
    int i = c*256 + t;
    int v = (i < NBS) ? bs[i] : 0;
    s[t] = v; __syncthreads();
    for (int d = 1; d < 256; d <<= 1) {
      int x = (t >= d) ? s[t-d] : 0;
      __syncthreads(); s[t] += x; __syncthreads();
    }
    int excl = s[t] - v + carry;
    if (i < NBS) bs[i] = excl;
    int tot = s[255]; __syncthreads();
    if (t == 0) carry += tot;
    __syncthreads();
  }
  if (t == 0) ((int*)(ws + START_OFF))[NATOM] = carry;
}
__global__ void k_scan3(char* ws) {
  int b = blockIdx.x, i = b*256 + threadIdx.x;
  if (i >= NATOM) return;
  int* start = (int*)(ws + START_OFF);
  int v = start[i] + ((int*)(ws + BS_OFF))[b];
  start[i] = v;
  ((int*)(ws + CUR_OFF))[i] = v;
}

// ---------------- scatter compact records ----------------
__global__ void k_scatter(const int* __restrict__ bonds, const int* __restrict__ A, char* ws) {
  int e = blockIdx.x*256 + threadIdx.x;
  if (e >= NEDGE) return;
  const unsigned char* gm = (const unsigned char*)(ws + GM_OFF);
  int src = bonds[e*3], dst = bonds[e*3+1];
  if (gm[src >> 3] | gm[dst >> 3]) return;
  int slot = atomicAdd((int*)(ws + CUR_OFF) + dst, 1);
  if (slot >= 0 && slot < NEDGE)
    ((unsigned short*)(ws + REC_OFF))[slot] = (unsigned short)(A[src]*5 + bonds[e*3+2]);
}

// ------------- GEMM core: 64 rows x 128 cols, 4 waves, 16x16x32 bf16 ------------
// A from LDS panels (256B row stride, XOR swizz byte^=(row&7)<<4), B from ws W^T.
template<int KB>
__device__ inline void gemm_core(const char* sm, const int* poff, const __bf16* wt,
                                 int wstride, const float* bias, float bscale,
                                 int lane, int wave, f32x4 acc[4][2]) {
  const int colA = wave*32 + (lane & 15);
  const int k0   = (lane >> 4) * 8;
  float bb0 = bias[colA] * bscale, bb1 = bias[colA + 16] * bscale;
  #pragma unroll
  for (int m = 0; m < 4; ++m) { acc[m][0] = splat4(bb0); acc[m][1] = splat4(bb1); }
  #pragma unroll
  for (int kb = 0; kb < KB; ++kb) {
    bf16x8 b0 = *(const bf16x8*)(wt + (long)colA*wstride + kb*32 + k0);
    bf16x8 b1 = *(const bf16x8*)(wt + (long)(colA+16)*wstride + kb*32 + k0);
    int base = poff[kb >> 2];
    #pragma unroll
    for (int m = 0; m < 4; ++m) {
      int rA = m*16 + (lane & 15);
      int byte = base + rA*256 + ((((kb & 3)*64) + k0*2) ^ ((rA & 7) << 4));
      bf16x8 a = *(const bf16x8*)(sm + byte);
      acc[m][0] = MFMA(a, b0, acc[m][0]);
      acc[m][1] = MFMA(a, b1, acc[m][1]);
    }
  }
}

__device__ inline void stor_lds_bf16(char* sm, int off, f32x4 acc[4][2],
                                     int lane, int wave, bool do_relu) {
  #pragma unroll
  for (int m = 0; m < 4; ++m)
  #pragma unroll
  for (int nf = 0; nf < 2; ++nf)
  #pragma unroll
  for (int r = 0; r < 4; ++r) {
    float v = acc[m][nf][r];
    if (do_relu && v < 0.f) v = 0.f;
    int row = m*16 + (lane >> 4)*4 + r;
    int col = wave*32 + nf*16 + (lane & 15);
    int byte = off + row*256 + ((col*2) ^ ((row & 7) << 4));
    *(__bf16*)(sm + byte) = (__bf16)v;
  }
}

// ---- fused: gather topo_pre -> GEMM2(topo) -> GEMM0(K384) -> GEMM1 -> GEMM3 ----
// LDS panels: pos@0, topo@16384, aa@32768 (each bf16[64][128], 256B stride, swizz);
// h1 reuses @0, h2 reuses @16384.
__launch_bounds__(256, 3)
__global__ void k_fused(char* ws, const int* __restrict__ A,
                        const int* __restrict__ pos_ids, const int* __restrict__ is_aa,
                        const float* cr, const float* aa_embed, const float* gb2,
                        const float* mb0, const float* mb1, const float* mb2,
                        float* __restrict__ out) {
  __shared__ __align__(16) char sm[49152];
  const int tid = threadIdx.x, lane = tid & 63, wave = tid >> 6;
  const int r0 = blockIdx.x * 64;
  const unsigned char* gm = (const unsigned char*)(ws + GM_OFF);
  const __bf16* pos_tab = (const __bf16*)(ws + POS_OFF);

  // stage pos panel (@0) and aa panel (@32768): 2048 chunks of 16B
  for (int i = 0; i < 8; ++i) {
    int idx = tid + i*256;
    int panel = idx >> 10;              // 0=pos, 1=aa
    int within = idx & 1023;
    int row = within >> 4, c = within & 15;
    int mol = r0 + row;
    bf16x8 v;
    if (mol < NBLK) {
      if (panel == 0) {
        v = *(const bf16x8*)(pos_tab + pos_ids[mol]*128 + c*8);
      } else {
        int corrupt = gm[mol] && (cr[mol] < 0.1f);
        int sel = corrupt ? 0 : is_aa[mol];
        const float* aaP = aa_embed + sel*128 + c*8;
        f32x4 a0 = *(const f32x4*)(aaP);
        f32x4 a1 = *(const f32x4*)(aaP + 4);
        #pragma unroll
        for (int j = 0; j < 4; ++j) { v[j] = (__bf16)a0[j]; v[j+4] = (__bf16)a1[j]; }
      }
    } else {
      #pragma unroll
      for (int j = 0; j < 8; ++j) v[j] = (__bf16)0.f;
    }
    int byte = (panel ? 32768 : 0) + row*256 + ((c*16) ^ ((row & 7) << 4));
    *(bf16x8*)(sm + byte) = v;
  }

  // gather phase: thread=(mol_local, quarter) -> topo_pre = sum_8 relu(EW1[A]+sum TW1)
  {
    const int ml = tid >> 2, q = tid & 3;
    const int mol = r0 + ml;
    float ms[32];
    #pragma unroll
    for (int k = 0; k < 32; ++k) ms[k] = 0.f;
    if (mol < NBLK && !gm[mol]) {
      const int* start = (const int*)(ws + START_OFF);
      const unsigned short* rec = (const unsigned short*)(ws + REC_OFF);
      const float* EW1 = (const float*)(ws + CUR_OFF);
      const float* TW1 = (const float*)(ws + T_OFF);
      int sa[9];
      #pragma unroll
      for (int a = 0; a < 9; ++a) sa[a] = start[mol*8 + a];
      #pragma unroll
      for (int a = 0; a < 8; ++a) {
        int aT = A[mol*8 + a];
        float u[32];
        const f32x4* ep = (const f32x4*)(EW1 + aT*128 + q*32);
        #pragma unroll
        for (int j = 0; j < 8; ++j) {
          f32x4 t = ep[j];
          #pragma unroll
          for (int k = 0; k < 4; ++k) u[j*4+k] = t[k];
        }
        int s0 = sa[a], s1 = sa[a+1];
        if (s0 < 0) s0 = 0;
        if (s1 > NEDGE) s1 = NEDGE;
        for (int s = s0; s < s1; ++s) {
          int p = rec[s];
          if (p >= 500) p = 0;
          const f32x4* tp = (const f32x4*)(TW1 + p*128 + q*32);
          #pragma unroll
          for (int j = 0; j < 8; ++j) {
            f32x4 t = tp[j];
            #pragma unroll
            for (int k = 0; k < 4; ++k) u[j*4+k] += t[k];
          }
        }
        #pragma unroll
        for (int k = 0; k < 32; ++k) ms[k] += fmaxf(u[k], 0.f);
      }
    }
    #pragma unroll
    for (int j = 0; j < 4; ++j) {
      bf16x8 o;
      #pragma unroll
      for (int k = 0; k < 8; ++k) o[k] = (__bf16)ms[j*8+k];
      int byte = 16384 + ml*256 + (((q*64) + j*16) ^ ((ml & 7) << 4));
      *(bf16x8*)(sm + byte) = o;
    }
  }
  __syncthreads();

  const int p_topo[3] = {16384, 16384, 16384};
  const int p_x[3]    = {0, 16384, 32768};
  const int p_h1[3]   = {0, 0, 0};
  const int p_h2[3]   = {16384, 16384, 16384};
  f32x4 acc[4][2];

  // GEMM2: topo = rs8*(topo_pre @ W2 + 8*b2), masked; write back into topo panel
  gemm_core<4>(sm, p_topo, (const __bf16*)(ws + G2T_OFF), 128, gb2, 8.0f, lane, wave, acc);
  __syncthreads();                       // all topo_pre reads done
  {
    const float rs8 = 0.35355339059327373f;
    #pragma unroll
    for (int m = 0; m < 4; ++m)
    #pragma unroll
    for (int nf = 0; nf < 2; ++nf)
    #pragma unroll
    for (int r = 0; r < 4; ++r) {
      int row = m*16 + (lane >> 4)*4 + r;
      int col = wave*32 + nf*16 + (lane & 15);
      int mol = r0 + row;
      float v = (mol < NBLK && !gm[mol]) ? scrub(acc[m][nf][r] * rs8) : 0.f;
      int byte = 16384 + row*256 + ((col*2) ^ ((row & 7) << 4));
      *(__bf16*)(sm + byte) = (__bf16)v;
    }
  }
  __syncthreads();

  // GEMM0: x=[pos|topo|aa] (K=384) @ W0 + b0, relu -> h1 @0
  gemm_core<12>(sm, p_x, (const __bf16*)(ws + M0T_OFF), 384, mb0, 1.0f, lane, wave, acc);
  __syncthreads();                       // all panel reads done
  stor_lds_bf16(sm, 0, acc, lane, wave, true);
  __syncthreads();

  // GEMM1 -> relu -> h2 @16384 (disjoint from h1; no barrier needed before store)
  gemm_core<4>(sm, p_h1, (const __bf16*)(ws + M1T_OFF), 128, mb1, 1.0f, lane, wave, acc);
  stor_lds_bf16(sm, 16384, acc, lane, wave, true);
  __syncthreads();

  // GEMM3 -> out
  gemm_core<4>(sm, p_h2, (const __bf16*)(ws + M2T_OFF), 128, mb2, 1.0f, lane, wave, acc);
  #pragma unroll
  for (int m = 0; m < 4; ++m)
  #pragma unroll
  for (int nf = 0; nf < 2; ++nf)
  #pragma unroll
  for (int r = 0; r < 4; ++r) {
    int row = m*16 + (lane >> 4)*4 + r;
    int col = wave*32 + nf*16 + (lane & 15);
    int mol = r0 + row;
    if (mol < NBLK) out[(long)mol*128 + col] = scrub(acc[m][nf][r]);
  }
}

extern "C" void kernel_launch(void* const* d_in, const int* in_sizes, int n_in,
                              void* d_out, int out_size, void* d_ws, size_t ws_size,
                              hipStream_t stream) {
  if (ws_size < WS_NEED) return;   // diagnostic: absmax-fail instead of fault
  const int* A      = (const int*)d_in[0];
  const int* bonds  = (const int*)d_in[1];
  // d_in[2] block_ids == arange//8, recomputed as atom>>3
  const void* gm    = d_in[3];
  const int* pos    = (const int*)d_in[4];
  const int* isaa   = (const int*)d_in[5];
  const float* cr   = (const float*)d_in[6];
  const float* atom_embed = (const float*)d_in[7];
  const float* bond_embed = (const float*)d_in[8];
  const float* aa_embed   = (const float*)d_in[9];
  const float* g1  = (const float*)d_in[10];
  const float* gb1 = (const float*)d_in[11];
  const float* g2  = (const float*)d_in[12];
  const float* gb2 = (const float*)d_in[13];
  const float* m0  = (const float*)d_in[14];
  const float* mb0 = (const float*)d_in[15];
  const float* m1  = (const float*)d_in[16];
  const float* mb1 = (const float*)d_in[17];
  const float* m2  = (const float*)d_in[18];
  const float* mb2 = (const float*)d_in[19];
  char* ws = (char*)d_ws;

  hipMemsetAsync(ws + START_OFF, 0, (size_t)(NATOM+1)*4, stream);
  k_sniff  <<<1, 256, 0, stream>>>(gm, ws);
  k_prep1  <<<1222, 128, 0, stream>>>(atom_embed, bond_embed, g2, m0, m1, m2, gm, ws);
  k_count  <<<3125, 256, 0, stream>>>(bonds, ws);
  k_scan1  <<<NBS, 256, 0, stream>>>(ws);
  k_scan2  <<<1, 256, 0, stream>>>(ws);
  k_scan3  <<<NBS, 256, 0, stream>>>(ws);
  k_scatter<<<3125, 256, 0, stream>>>(bonds, A, ws);
  k_prep2  <<<600, 128, 0, stream>>>(atom_embed, g1, gb1, ws);   // EW1 -> CUR, TW1 in place
  k_fused  <<<(NBLK + 63)/64, 256, 0, stream>>>(ws, A, pos, isaa, cr, aa_embed,
                                                gb2, mb0, mb1, mb2, (float*)d_out);
}

// Round 8
// 155.974 us; speedup vs baseline: 1.4233x; 1.4233x over previous
//
#include <hip/hip_runtime.h>
#include <hip/hip_bf16.h>

#define NBLK  50000
#define NATOM 400000
#define NEDGE 800000
#define NBS   1563            // ceil(400000/256)

typedef __bf16 bf16x8 __attribute__((ext_vector_type(8)));
typedef __bf16 bf16x4 __attribute__((ext_vector_type(4)));
typedef float  f32x4  __attribute__((ext_vector_type(4)));

// ---- workspace layout (bytes); WS_NEED = round-5/6-proven 18,403,840 ----
#define START_OFF 0UL          // int32[400001]: counts -> exclusive offsets (+total)
#define CUR_OFF   1600016UL    // int32[400000]: cursors; REUSED as EW1 f32[100][128] after k_scatter
#define BS_OFF    3200016UL    // int32[1563]
#define REC_OFF   3206288UL    // u16 [800000]: per-edge pair ids, CSR by dst atom
#define T_OFF     4806288UL    // f32 [500][128]: msg table; REWRITTEN IN PLACE to TW1 = T@W1
#define POS_OFF   5062288UL    // bf16[1024][128] sinusoid table
#define G2T_OFF   5357200UL    // bf16[128][128] gine_w2^T
#define M0T_OFF   5389968UL    // bf16[128][384] mlp_w0^T
#define M1T_OFF   5488272UL    // bf16[128][128] mlp_w1^T
#define M2T_OFF   5521040UL    // bf16[128][128] mlp_w2^T
#define GM_OFF    5553808UL    // u8 [50000] canonical generate_mask
#define FLAG_OFF  5603808UL    // int32 dtype-sniff flag
#define TOPO_OFF  5603840UL    // bf16[50000][128] topo_pre = sum_8 relu(h1)
#define WS_NEED   18403840UL

#define MFMA(a,b,c) __builtin_amdgcn_mfma_f32_16x16x32_bf16((a),(b),(c),0,0,0)

__device__ inline f32x4 splat4(float v){ f32x4 r; r[0]=v; r[1]=v; r[2]=v; r[3]=v; return r; }
__device__ inline float scrub(float v){ return (v==v && v<1e30f && v>-1e30f) ? v : 0.f; }

// ---------------- dtype sniff for generate_mask (1 block) ----------------
__global__ void k_sniff(const void* gm_raw, char* ws) {
  __shared__ int big;
  if (threadIdx.x == 0) big = 0;
  __syncthreads();
  const unsigned* gw = (const unsigned*)gm_raw;
  for (int i = threadIdx.x; i < 12500; i += 256)
    if (gw[i] > 1u) big = 1;
  __syncthreads();
  if (threadIdx.x == 0) *(int*)(ws + FLAG_OFF) = big;
}

// ------------- prep1: msg table T, sinusoid, W^T (f32->bf16), gm canon ----------
__global__ void k_prep1(const float* atom_embed, const float* bond_embed,
                        const float* g2, const float* m0, const float* m1,
                        const float* m2, const void* gm_raw, char* ws) {
  int b = blockIdx.x, t = threadIdx.x;
  if (b < 100) {                       // T[a*5+bond][c] = relu(ae + be), f32
    float ae = atom_embed[b*128 + t];
    float* T = (float*)(ws + T_OFF);
    for (int bo = 0; bo < 5; ++bo) {
      float v = ae + bond_embed[bo*128 + t];
      T[(b*5 + bo)*128 + t] = v > 0.f ? v : 0.f;
    }
  } else if (b < 1124) {               // sinusoidal table, bf16, fast-math
    int p = b - 100;
    __bf16* P = (__bf16*)(ws + POS_OFF);
    int c = t & 63;
    float invf = exp2f((float)c * -0.20762050593046012f);  // 10000^(-c/64)
    float ang = (float)p * invf;
    float v = (t < 64) ? __sinf(ang) : __cosf(ang);
    P[p*128 + t] = (__bf16)v;
  } else if (b < 1172) {               // weight transposes f32 -> bf16 [n][k]
    int wb = b - 1124;
    const float* src; __bf16* dst; int K; int r0;
    if (wb < 8)       { src = g2; dst = (__bf16*)(ws + G2T_OFF); K = 128; r0 = wb*16; }
    else if (wb < 32) { src = m0; dst = (__bf16*)(ws + M0T_OFF); K = 384; r0 = (wb-8)*16; }
    else if (wb < 40) { src = m1; dst = (__bf16*)(ws + M1T_OFF); K = 128; r0 = (wb-32)*16; }
    else              { src = m2; dst = (__bf16*)(ws + M2T_OFF); K = 128; r0 = (wb-40)*16; }
    for (int rr = 0; rr < 16; ++rr) {
      int r = r0 + rr;
      dst[t*K + r] = (__bf16)src[r*128 + t];
    }
  } else {                             // gm canon: 50 blocks x 1000 elems
    int anyBig = *(const int*)(ws + FLAG_OFF);
    int base = (b - 1172) * 1000;
    unsigned char* gu = (unsigned char*)(ws + GM_OFF);
    if (anyBig) {
      const unsigned char* gb = (const unsigned char*)gm_raw;
      for (int i = t; i < 1000; i += 128) gu[base+i] = gb[base+i] ? 1 : 0;
    } else {
      const int* gi = (const int*)gm_raw;
      for (int i = t; i < 1000; i += 128) gu[base+i] = gi[base+i] ? 1 : 0;
    }
  }
}

// ------- prep2: EW1 = emb@W1+b1 (->CUR region), TW1 = T@W1 (in place over T) -----
__global__ void k_prep2(const float* atom_embed, const float* g1, const float* gb1,
                        char* ws) {
  int b = blockIdx.x, t = threadIdx.x;   // t = output col
  if (b < 100) {
    float s = gb1[t];
    const float* row = atom_embed + b*128;
    for (int k = 0; k < 128; ++k) s += row[k] * g1[k*128 + t];
    ((float*)(ws + CUR_OFF))[b*128 + t] = s;
  } else {
    int r = b - 100;                     // T row
    float* T = (float*)(ws + T_OFF);
    const float* row = T + r*128;
    float s = 0.f;
    for (int k = 0; k < 128; ++k) s += row[k] * g1[k*128 + t];
    __syncthreads();                     // all reads of row r done before overwrite
    T[r*128 + t] = s;                    // in-place TW1 (bias enters via EW1)
  }
}

// ---------------- count valid in-edges per dst atom ----------------
__global__ void k_count(const int* __restrict__ bonds, char* ws) {
  int e = blockIdx.x*256 + threadIdx.x;
  if (e >= NEDGE) return;
  const unsigned char* gm = (const unsigned char*)(ws + GM_OFF);
  int src = bonds[e*3], dst = bonds[e*3+1];
  if (gm[src >> 3] | gm[dst >> 3]) return;
  atomicAdd((int*)(ws + START_OFF) + dst, 1);
}

// ---------------- exclusive scan over 400000 counts (3 kernels) ----------------
__global__ void k_scan1(char* ws) {
  __shared__ int s[256];
  int b = blockIdx.x, t = threadIdx.x, i = b*256 + t;
  int* cnt = (int*)(ws + START_OFF);
  int v = (i < NATOM) ? cnt[i] : 0;
  s[t] = v; __syncthreads();
  for (int d = 1; d < 256; d <<= 1) {
    int x = (t >= d) ? s[t-d] : 0;
    __syncthreads(); s[t] += x; __syncthreads();
  }
  if (i < NATOM) cnt[i] = s[t] - v;
  if (t == 255) ((int*)(ws + BS_OFF))[b] = s[255];
}
__global__ void k_scan2(char* ws) {
  __shared__ int s[256]; __shared__ int carry;
  int t = threadIdx.x;
  int* bs = (int*)(ws + BS_OFF);
  if (t == 0) carry = 0;
  __syncthreads();
  for (int c = 0; c < 7; ++c) {
    int i = c*256 + t;
    int v = (i < NBS) ? bs[i] : 0;
    s[t] = v; __syncthreads();
    for (int d = 1; d < 256; d <<= 1) {
      int x = (t >= d) ? s[t-d] : 0;
      __syncthreads(); s[t] += x; __syncthreads();
    }
    int excl = s[t] - v + carry;
    if (i < NBS) bs[i] = excl;
    int tot = s[255]; __syncthreads();
    if (t == 0) carry += tot;
    __syncthreads();
  }
  if (t == 0) ((int*)(ws + START_OFF))[NATOM] = carry;
}
__global__ void k_scan3(char* ws) {
  int b = blockIdx.x, i = b*256 + threadIdx.x;
  if (i >= NATOM) return;
  int* start = (int*)(ws + START_OFF);
  int v = start[i] + ((int*)(ws + BS_OFF))[b];
  start[i] = v;
  ((int*)(ws + CUR_OFF))[i] = v;
}

// ---------------- scatter compact records ----------------
__global__ void k_scatter(const int* __restrict__ bonds, const int* __restrict__ A, char* ws) {
  int e = blockIdx.x*256 + threadIdx.x;
  if (e >= NEDGE) return;
  const unsigned char* gm = (const unsigned char*)(ws + GM_OFF);
  int src = bonds[e*3], dst = bonds[e*3+1];
  if (gm[src >> 3] | gm[dst >> 3]) return;
  int slot = atomicAdd((int*)(ws + CUR_OFF) + dst, 1);
  if (slot >= 0 && slot < NEDGE)
    ((unsigned short*)(ws + REC_OFF))[slot] = (unsigned short)(A[src]*5 + bonds[e*3+2]);
}

// ---- gather: per atom u = relu(EW1[A] + sum TW1[rec]); per mol sum_8 -> topo_pre ----
// Round-6-proven register shape: u[32] only. LDS [64][128] bf16 swizzled.
__launch_bounds__(256, 6)
__global__ void k_gather(char* ws, const int* __restrict__ A) {
  __shared__ __align__(16) char sm[16384];
  const int tid = threadIdx.x;
  const int row0 = blockIdx.x * 64;                 // atom base
  const unsigned char* gm = (const unsigned char*)(ws + GM_OFF);

  // phase 1: thread=(atom rowL, quarter q): u[32] f32, relu, bf16 -> LDS
  {
    const int rowL = tid >> 2, q = tid & 3;
    const int atom = row0 + rowL;
    float u[32];
    #pragma unroll
    for (int k = 0; k < 32; ++k) u[k] = 0.f;
    if (!gm[atom >> 3]) {
      const int* start = (const int*)(ws + START_OFF);
      const unsigned short* rec = (const unsigned short*)(ws + REC_OFF);
      const float* EW1 = (const float*)(ws + CUR_OFF);
      const float* TW1 = (const float*)(ws + T_OFF);
      int aT = A[atom];
      const f32x4* ep = (const f32x4*)(EW1 + aT*128 + q*32);
      #pragma unroll
      for (int j = 0; j < 8; ++j) {
        f32x4 t = ep[j];
        #pragma unroll
        for (int k = 0; k < 4; ++k) u[j*4+k] = t[k];
      }
      int s0 = start[atom], s1 = start[atom+1];
      if (s0 < 0) s0 = 0;
      if (s1 > NEDGE) s1 = NEDGE;
      for (int s = s0; s < s1; ++s) {
        int p = rec[s];
        if (p >= 500) p = 0;
        const f32x4* tp = (const f32x4*)(TW1 + p*128 + q*32);
        #pragma unroll
        for (int j = 0; j < 8; ++j) {
          f32x4 t = tp[j];
          #pragma unroll
          for (int k = 0; k < 4; ++k) u[j*4+k] += t[k];
        }
      }
    }
    #pragma unroll
    for (int j = 0; j < 4; ++j) {
      bf16x8 o;
      #pragma unroll
      for (int k = 0; k < 8; ++k) o[k] = (__bf16)fmaxf(u[j*8+k], 0.f);
      int byte = rowL*256 + (((q*64) + j*16) ^ ((rowL & 7) << 4));
      *(bf16x8*)(sm + byte) = o;
    }
  }
  __syncthreads();

  // phase 2: thread=(mol ml 0..7, col-chunk cs 0..31): sum 8 rows x 4 cols
  {
    const int ml = tid >> 5, cs = tid & 31;
    const int mol = (row0 >> 3) + ml;
    float s0 = 0.f, s1 = 0.f, s2 = 0.f, s3 = 0.f;
    #pragma unroll
    for (int r = 0; r < 8; ++r) {
      int row = ml*8 + r;
      int byte = row*256 + ((cs*8) ^ ((row & 7) << 4));
      bf16x4 v = *(const bf16x4*)(sm + byte);
      s0 += (float)v[0]; s1 += (float)v[1]; s2 += (float)v[2]; s3 += (float)v[3];
    }
    bf16x4 o;
    o[0] = (__bf16)s0; o[1] = (__bf16)s1; o[2] = (__bf16)s2; o[3] = (__bf16)s3;
    *(bf16x4*)((char*)ws + TOPO_OFF + (long)mol*256 + cs*8) = o;
  }
}

// ------------- GEMM core: 64 rows x 128 cols, 4 waves, 16x16x32 bf16 ------------
template<int KB>
__device__ inline void gemm_core(const char* sm, const int* poff, const __bf16* wt,
                                 int wstride, const float* bias, float bscale,
                                 int lane, int wave, f32x4 acc[4][2]) {
  const int colA = wave*32 + (lane & 15);
  const int k0   = (lane >> 4) * 8;
  float bb0 = bias[colA] * bscale, bb1 = bias[colA + 16] * bscale;
  #pragma unroll
  for (int m = 0; m < 4; ++m) { acc[m][0] = splat4(bb0); acc[m][1] = splat4(bb1); }
  #pragma unroll
  for (int kb = 0; kb < KB; ++kb) {
    bf16x8 b0 = *(const bf16x8*)(wt + (long)colA*wstride + kb*32 + k0);
    bf16x8 b1 = *(const bf16x8*)(wt + (long)(colA+16)*wstride + kb*32 + k0);
    int base = poff[kb >> 2];
    #pragma unroll
    for (int m = 0; m < 4; ++m) {
      int rA = m*16 + (lane & 15);
      int byte = base + rA*256 + ((((kb & 3)*64) + k0*2) ^ ((rA & 7) << 4));
      bf16x8 a = *(const bf16x8*)(sm + byte);
      acc[m][0] = MFMA(a, b0, acc[m][0]);
      acc[m][1] = MFMA(a, b1, acc[m][1]);
    }
  }
}

__device__ inline void stor_lds_bf16(char* sm, int off, f32x4 acc[4][2],
                                     int lane, int wave, bool do_relu) {
  #pragma unroll
  for (int m = 0; m < 4; ++m)
  #pragma unroll
  for (int nf = 0; nf < 2; ++nf)
  #pragma unroll
  for (int r = 0; r < 4; ++r) {
    float v = acc[m][nf][r];
    if (do_relu && v < 0.f) v = 0.f;
    int row = m*16 + (lane >> 4)*4 + r;
    int col = wave*32 + nf*16 + (lane & 15);
    int byte = off + row*256 + ((col*2) ^ ((row & 7) << 4));
    *(__bf16*)(sm + byte) = (__bf16)v;
  }
}

// ---- mlp2: stage pos/topo_pre/aa -> GEMM2(topo) -> GEMM0(K384) -> GEMM1 -> GEMM3 ----
// LDS panels: pos@0, topo@16384, aa@32768; h1 reuses @0, h2 reuses @16384.
__launch_bounds__(256, 3)
__global__ void k_mlp2(char* ws, const int* __restrict__ pos_ids, const int* __restrict__ is_aa,
                       const float* cr, const float* aa_embed, const float* gb2,
                       const float* mb0, const float* mb1, const float* mb2,
                       float* __restrict__ out) {
  __shared__ __align__(16) char sm[49152];
  const int tid = threadIdx.x, lane = tid & 63, wave = tid >> 6;
  const int r0 = blockIdx.x * 64;
  const unsigned char* gm = (const unsigned char*)(ws + GM_OFF);
  const __bf16* pos_tab = (const __bf16*)(ws + POS_OFF);
  const __bf16* topo_pre = (const __bf16*)(ws + TOPO_OFF);

  // stage pos@0, topo@16384, aa@32768: 3072 chunks of 16B
  for (int i = 0; i < 12; ++i) {
    int idx = tid + i*256;
    int panel = idx >> 10;              // 0=pos, 1=topo, 2=aa
    int within = idx & 1023;
    int row = within >> 4, c = within & 15;
    int mol = r0 + row;
    bf16x8 v;
    if (mol < NBLK) {
      if (panel == 0) {
        v = *(const bf16x8*)(pos_tab + pos_ids[mol]*128 + c*8);
      } else if (panel == 1) {
        v = *(const bf16x8*)(topo_pre + (long)mol*128 + c*8);
      } else {
        int corrupt = gm[mol] && (cr[mol] < 0.1f);
        int sel = corrupt ? 0 : is_aa[mol];
        const float* aaP = aa_embed + sel*128 + c*8;
        f32x4 a0 = *(const f32x4*)(aaP);
        f32x4 a1 = *(const f32x4*)(aaP + 4);
        #pragma unroll
        for (int j = 0; j < 4; ++j) { v[j] = (__bf16)a0[j]; v[j+4] = (__bf16)a1[j]; }
      }
    } else {
      #pragma unroll
      for (int j = 0; j < 8; ++j) v[j] = (__bf16)0.f;
    }
    int byte = panel*16384 + row*256 + ((c*16) ^ ((row & 7) << 4));
    *(bf16x8*)(sm + byte) = v;
  }
  __syncthreads();

  const int p_topo[1] = {16384};
  const int p_x[3]    = {0, 16384, 32768};
  const int p_h1[1]   = {0};
  const int p_h2[1]   = {16384};
  f32x4 acc[4][2];

  // GEMM2: topo = rs8*(topo_pre @ W2 + 8*b2), masked; rewrite topo panel
  gemm_core<4>(sm, p_topo, (const __bf16*)(ws + G2T_OFF), 128, gb2, 8.0f, lane, wave, acc);
  __syncthreads();
  {
    const float rs8 = 0.35355339059327373f;
    #pragma unroll
    for (int m = 0; m < 4; ++m)
    #pragma unroll
    for (int nf = 0; nf < 2; ++nf)
    #pragma unroll
    for (int r = 0; r < 4; ++r) {
      int row = m*16 + (lane >> 4)*4 + r;
      int col = wave*32 + nf*16 + (lane & 15);
      int mol = r0 + row;
      float v = (mol < NBLK && !gm[mol]) ? scrub(acc[m][nf][r] * rs8) : 0.f;
      int byte = 16384 + row*256 + ((col*2) ^ ((row & 7) << 4));
      *(__bf16*)(sm + byte) = (__bf16)v;
    }
  }
  __syncthreads();

  // GEMM0: x=[pos|topo|aa] (K=384) @ W0 + b0, relu -> h1 @0
  gemm_core<12>(sm, p_x, (const __bf16*)(ws + M0T_OFF), 384, mb0, 1.0f, lane, wave, acc);
  __syncthreads();
  stor_lds_bf16(sm, 0, acc, lane, wave, true);
  __syncthreads();

  // GEMM1 -> relu -> h2 @16384
  gemm_core<4>(sm, p_h1, (const __bf16*)(ws + M1T_OFF), 128, mb1, 1.0f, lane, wave, acc);
  stor_lds_bf16(sm, 16384, acc, lane, wave, true);
  __syncthreads();

  // GEMM3 -> out
  gemm_core<4>(sm, p_h2, (const __bf16*)(ws + M2T_OFF), 128, mb2, 1.0f, lane, wave, acc);
  #pragma unroll
  for (int m = 0; m < 4; ++m)
  #pragma unroll
  for (int nf = 0; nf < 2; ++nf)
  #pragma unroll
  for (int r = 0; r < 4; ++r) {
    int row = m*16 + (lane >> 4)*4 + r;
    int col = wave*32 + nf*16 + (lane & 15);
    int mol = r0 + row;
    if (mol < NBLK) out[(long)mol*128 + col] = scrub(acc[m][nf][r]);
  }
}

extern "C" void kernel_launch(void* const* d_in, const int* in_sizes, int n_in,
                              void* d_out, int out_size, void* d_ws, size_t ws_size,
                              hipStream_t stream) {
  if (ws_size < WS_NEED) return;   // diagnostic: absmax-fail instead of fault
  const int* A      = (const int*)d_in[0];
  const int* bonds  = (const int*)d_in[1];
  const void* gm    = d_in[3];
  const int* pos    = (const int*)d_in[4];
  const int* isaa   = (const int*)d_in[5];
  const float* cr   = (const float*)d_in[6];
  const float* atom_embed = (const float*)d_in[7];
  const float* bond_embed = (const float*)d_in[8];
  const float* aa_embed   = (const float*)d_in[9];
  const float* g1  = (const float*)d_in[10];
  const float* gb1 = (const float*)d_in[11];
  const float* g2  = (const float*)d_in[12];
  const float* gb2 = (const float*)d_in[13];
  const float* m0  = (const float*)d_in[14];
  const float* mb0 = (const float*)d_in[15];
  const float* m1  = (const float*)d_in[16];
  const float* mb1 = (const float*)d_in[17];
  const float* m2  = (const float*)d_in[18];
  const float* mb2 = (const float*)d_in[19];
  char* ws = (char*)d_ws;

  hipMemsetAsync(ws + START_OFF, 0, (size_t)(NATOM+1)*4, stream);
  k_sniff  <<<1, 256, 0, stream>>>(gm, ws);
  k_prep1  <<<1222, 128, 0, stream>>>(atom_embed, bond_embed, g2, m0, m1, m2, gm, ws);
  k_count  <<<3125, 256, 0, stream>>>(bonds, ws);
  k_scan1  <<<NBS, 256, 0, stream>>>(ws);
  k_scan2  <<<1, 256, 0, stream>>>(ws);
  k_scan3  <<<NBS, 256, 0, stream>>>(ws);
  k_scatter<<<3125, 256, 0, stream>>>(bonds, A, ws);
  k_prep2  <<<600, 128, 0, stream>>>(atom_embed, g1, gb1, ws);   // EW1 -> CUR, TW1 in place
  k_gather <<<NATOM/64, 256, 0, stream>>>(ws, A);
  k_mlp2   <<<(NBLK + 63)/64, 256, 0, stream>>>(ws, pos, isaa, cr, aa_embed,
                                                gb2, mb0, mb1, mb2, (float*)d_out);
}